// Round 12
// baseline (401.296 us; speedup 1.0000x reference)
//
#include <hip/hip_runtime.h>

#define T_    1024
#define H_    2048
#define NH_   16
#define NKV_  4
#define HD_   128
#define E_    16
#define I_    768
#define QKVN  3072

typedef __attribute__((ext_vector_type(8))) short  short8;
typedef __attribute__((ext_vector_type(4))) float  f32x4;
typedef unsigned short u16;

#define LDP 40   // padded LDS K-stride (bf16): 80B rows, 2-way banks at worst (free)

__device__ inline u16 f2bf(float f) {
  unsigned u = __builtin_bit_cast(unsigned, f);
  return (u16)((u + 0x7fffu + ((u >> 16) & 1u)) >> 16);
}
__device__ inline float bf2f(u16 h) {
  unsigned u = ((unsigned)h) << 16;
  return __builtin_bit_cast(float, u);
}

__device__ inline float blk_sum(float v, float* lds) {
#pragma unroll
  for (int o = 32; o; o >>= 1) v += __shfl_down(v, o);
  int w = threadIdx.x >> 6;
  __syncthreads();
  if ((threadIdx.x & 63) == 0) lds[w] = v;
  __syncthreads();
  float s = lds[0];
  int nw = blockDim.x >> 6;
  for (int i = 1; i < nw; ++i) s += lds[i];
  return s;
}
__device__ inline float blk_max(float v, float* lds) {
#pragma unroll
  for (int o = 32; o; o >>= 1) v = fmaxf(v, __shfl_down(v, o));
  int w = threadIdx.x >> 6;
  __syncthreads();
  if ((threadIdx.x & 63) == 0) lds[w] = v;
  __syncthreads();
  float s = lds[0];
  int nw = blockDim.x >> 6;
  for (int i = 1; i < nw; ++i) s = fmaxf(s, lds[i]);
  return s;
}

// ======== bf16-B GEMM template (scores/pv), r9-proven: 512t, 8 waves 4Mx2N ========
// Tile 128 x 64 x 32, wave tile 32x32, acc[2][2].

struct AU4 { uint4 v; };       // A bf16: 128 rows x 32 k; row=tid>>2, kg=(tid&3)*8
struct BU2 { uint2 v; };       // B bf16: 64 rows x 32 k; row=tid>>3, kg=(tid&7)*4
struct F2  { float v[2]; };    // B fp32: 32 cols x 32 k; n=tid&31, kh=(tid>>5)*2

__device__ inline void wrS(u16* lds, const AU4& r) {
  *(uint4*)(lds + (threadIdx.x >> 2) * LDP + (threadIdx.x & 3) * 8) = r.v;
}
__device__ inline void wrS(u16* lds, const BU2& r) {
  *(uint2*)(lds + (threadIdx.x >> 3) * LDP + (threadIdx.x & 7) * 4) = r.v;
}
__device__ inline void wrS(u16* lds, const F2& r) {
  int n = threadIdx.x & 31, kh = (threadIdx.x >> 5) * 2;
  unsigned w = (unsigned)f2bf(r.v[0]) | ((unsigned)f2bf(r.v[1]) << 16);
  *(unsigned*)(lds + n * LDP + kh) = w;
}

__device__ inline void mma2(const u16* As, const u16* Bs, f32x4 acc[2][2]) {
  const int lane = threadIdx.x & 63, wv = threadIdx.x >> 6;
  const int wr = wv >> 1, wc = wv & 1;
  const int kk = (lane >> 4) * 8, rr = lane & 15;
  short8 aF[2], bF[2];
#pragma unroll
  for (int m = 0; m < 2; ++m)
    aF[m] = *(const short8*)(As + (wr * 32 + m * 16 + rr) * LDP + kk);
#pragma unroll
  for (int n = 0; n < 2; ++n)
    bF[n] = *(const short8*)(Bs + (wc * 32 + n * 16 + rr) * LDP + kk);
#pragma unroll
  for (int m = 0; m < 2; ++m)
#pragma unroll
    for (int n = 0; n < 2; ++n)
      acc[m][n] = __builtin_amdgcn_mfma_f32_16x16x32_bf16(aF[m], bF[n], acc[m][n], 0, 0, 0);
}

#define ZERO_ACC4(acc) do { \
  _Pragma("unroll") for (int m_ = 0; m_ < 2; ++m_) \
  _Pragma("unroll") for (int n_ = 0; n_ < 2; ++n_) acc[m_][n_] = (f32x4){0.f,0.f,0.f,0.f}; \
} while (0)

#define EPI_ROW(m, r)  (((threadIdx.x >> 6) >> 1) * 32 + (m)*16 + (((threadIdx.x&63) >> 4) * 4) + (r))
#define EPI_COL(n)     ((((threadIdx.x >> 6) & 1) * 32) + (n)*16 + ((threadIdx.x&63) & 15))

template<int NT, class AT, class BT, class LA, class LB>
__device__ inline void pipe2(LA la, LB lb, u16* A0, u16* B0, u16* A1, u16* B1,
                             f32x4 acc[2][2]) {
  AT a0, a1; BT b0, b1;
  la(a0, 0); lb(b0, 0);
  la(a1, 1); lb(b1, 1);
  wrS(A0, a0); wrS(B0, b0);
  if (NT > 2) { la(a0, 2); lb(b0, 2); }
#pragma unroll 1
  for (int kt = 0; kt < NT; kt += 2) {
    __syncthreads();
    wrS(A1, a1); wrS(B1, b1);
    if (kt + 3 < NT) { la(a1, kt + 3); lb(b1, kt + 3); }
    mma2(A0, B0, acc);
    __syncthreads();
    if (kt + 2 < NT) { wrS(A0, a0); wrS(B0, b0); }
    if (kt + 4 < NT) { la(a0, kt + 4); lb(b0, kt + 4); }
    mma2(A1, B1, acc);
  }
}

// ======== fp32-weight GEMM template (N-split): 512t, 8 waves 8Mx1N ========
// Tile 128 x 32 x 32, wave tile 16x32, acc[2] (8 VGPR). BN=32 halves weight-panel
// width -> 2x blocks, weight bytes still read EXACTLY once (N-split, not M-split:
// r10 lesson). 3-4 co-resident blocks/CU overlap barrier-drain stalls.

__device__ inline void mma12(const u16* As, const u16* Bs, f32x4 acc[2]) {
  const int lane = threadIdx.x & 63, wv = threadIdx.x >> 6;
  const int kk = (lane >> 4) * 8, rr = lane & 15;
  short8 aF = *(const short8*)(As + (wv * 16 + rr) * LDP + kk);
#pragma unroll
  for (int n = 0; n < 2; ++n) {
    short8 bF = *(const short8*)(Bs + (n * 16 + rr) * LDP + kk);
    acc[n] = __builtin_amdgcn_mfma_f32_16x16x32_bf16(aF, bF, acc[n], 0, 0, 0);
  }
}

#define ZERO_ACC2(acc) do { \
  _Pragma("unroll") for (int n_ = 0; n_ < 2; ++n_) acc[n_] = (f32x4){0.f,0.f,0.f,0.f}; \
} while (0)

#define EPIW_ROW(r)  ((threadIdx.x >> 6) * 16 + (((threadIdx.x&63) >> 4) * 4) + (r))
#define EPIW_COL(n)  ((n)*16 + ((threadIdx.x&63) & 15))

template<int NT, class LA, class LB>
__device__ inline void pipeW(LA la, LB lb, u16* A0, u16* B0, u16* A1, u16* B1,
                             f32x4 acc[2]) {
  AU4 a0, a1; F2 b0, b1;
  la(a0, 0); lb(b0, 0);
  la(a1, 1); lb(b1, 1);
  wrS(A0, a0); wrS(B0, b0);
  if (NT > 2) { la(a0, 2); lb(b0, 2); }
#pragma unroll 1
  for (int kt = 0; kt < NT; kt += 2) {
    __syncthreads();
    wrS(A1, a1); wrS(B1, b1);
    if (kt + 3 < NT) { la(a1, kt + 3); lb(b1, kt + 3); }
    mma12(A0, B0, acc);
    __syncthreads();
    if (kt + 2 < NT) { wrS(A0, a0); wrS(B0, b0); }
    if (kt + 4 < NT) { la(a0, kt + 4); lb(b0, kt + 4); }
    mma12(A1, B1, acc);
  }
}

// ---------------- kernels ----------------

__global__ __launch_bounds__(256) void k_rms1(const float* x, const float* w, u16* out) {
  __shared__ float lds[4];
  int t = blockIdx.x, tid = threadIdx.x;
  float v[8]; float ss = 0.f;
#pragma unroll
  for (int i = 0; i < 8; ++i) { v[i] = x[(size_t)t * H_ + tid + 256 * i]; ss += v[i] * v[i]; }
  ss = blk_sum(ss, lds);
  float inv = rsqrtf(ss * (1.f / H_) + 1e-6f);
#pragma unroll
  for (int i = 0; i < 8; ++i)
    out[(size_t)t * H_ + tid + 256 * i] = f2bf(v[i] * inv * w[tid + 256 * i]);
}

__global__ __launch_bounds__(256) void k_rms2(const float* x, const float* w,
                                              float* outf, u16* outb) {
  __shared__ float lds[4];
  int t = blockIdx.x, tid = threadIdx.x;
  float v[8]; float ss = 0.f;
#pragma unroll
  for (int i = 0; i < 8; ++i) { v[i] = x[(size_t)t * H_ + tid + 256 * i]; ss += v[i] * v[i]; }
  ss = blk_sum(ss, lds);
  float inv = rsqrtf(ss * (1.f / H_) + 1e-6f);
#pragma unroll
  for (int i = 0; i < 8; ++i) {
    float r = v[i] * inv * w[tid + 256 * i];
    outf[(size_t)t * H_ + tid + 256 * i] = r;
    outb[(size_t)t * H_ + tid + 256 * i] = f2bf(r);
  }
}

// qkv: [1024 x 3072 x 2048], BN=32. grid (96, 8) = 768 blocks
__global__ __launch_bounds__(512) void k_qkv(const u16* h1, const float* wqkv, float* qkv) {
  __shared__ __align__(16) u16 A0[128 * LDP], B0[32 * LDP], A1[128 * LDP], B1[32 * LDP];
  int bn = blockIdx.x, bm = blockIdx.y;
  f32x4 acc[2]; ZERO_ACC2(acc);
  auto la = [&](AU4& r, int kt) {
    r.v = *(const uint4*)(h1 + (size_t)(bm * 128 + (threadIdx.x >> 2)) * H_ + kt * 32 + (threadIdx.x & 3) * 8);
  };
  auto lb = [&](F2& r, int kt) {
    int n = threadIdx.x & 31, kh = (threadIdx.x >> 5) * 2;
    const float* src = wqkv + (size_t)(kt * 32 + kh) * QKVN + bn * 32 + n;
    r.v[0] = src[0]; r.v[1] = src[QKVN];
  };
  pipeW<H_ / 32>(la, lb, A0, B0, A1, B1, acc);
#pragma unroll
  for (int n = 0; n < 2; ++n) {
    f32x4 a = acc[n];
#pragma unroll
    for (int r = 0; r < 4; ++r)
      qkv[(size_t)(bm * 128 + EPIW_ROW(r)) * QKVN + bn * 32 + EPIW_COL(n)] = a[r];
  }
}

__global__ __launch_bounds__(256) void k_qkrope(const float* qkv, const int* pos,
                                                const float* wq, const float* wk,
                                                u16* q, u16* kk, u16* vT) {
  __shared__ float cs[64], sn[64];
  int t = blockIdx.x, tid = threadIdx.x, lane = tid & 63, w = tid >> 6;
  if (tid < 64) {
    float fr = expf(-((float)tid / 64.f) * 9.210340371976184f);
    float ang = (float)pos[t] * fr;
    float s_, c_; sincosf(ang, &s_, &c_);
    cs[tid] = c_; sn[tid] = s_;
  }
  __syncthreads();
  const float* row = qkv + (size_t)t * QKVN;
  for (int h = w; h < NH_; h += 4) {
    float x1 = row[h * 128 + lane], x2 = row[h * 128 + 64 + lane];
    float ss = x1 * x1 + x2 * x2;
#pragma unroll
    for (int o = 32; o; o >>= 1) ss += __shfl_down(ss, o);
    ss = __shfl(ss, 0);
    float inv = rsqrtf(ss * (1.f / HD_) + 1e-6f);
    float n1 = x1 * inv * wq[lane], n2 = x2 * inv * wq[64 + lane];
    float o1 = n1 * cs[lane] - n2 * sn[lane];
    float o2 = n2 * cs[lane] + n1 * sn[lane];
    q[(size_t)t * (NH_ * HD_) + h * 128 + lane] = f2bf(o1);
    q[(size_t)t * (NH_ * HD_) + h * 128 + 64 + lane] = f2bf(o2);
  }
  if (w < NKV_) {
    int h = w;
    float x1 = row[2048 + h * 128 + lane], x2 = row[2048 + h * 128 + 64 + lane];
    float ss = x1 * x1 + x2 * x2;
#pragma unroll
    for (int o = 32; o; o >>= 1) ss += __shfl_down(ss, o);
    ss = __shfl(ss, 0);
    float inv = rsqrtf(ss * (1.f / HD_) + 1e-6f);
    float n1 = x1 * inv * wk[lane], n2 = x2 * inv * wk[64 + lane];
    float o1 = n1 * cs[lane] - n2 * sn[lane];
    float o2 = n2 * cs[lane] + n1 * sn[lane];
    kk[((size_t)h * T_ + t) * HD_ + lane] = f2bf(o1);
    kk[((size_t)h * T_ + t) * HD_ + 64 + lane] = f2bf(o2);
    float v1 = row[2560 + h * 128 + lane], v2 = row[2560 + h * 128 + 64 + lane];
    vT[((size_t)(h * 128 + lane)) * T_ + t] = f2bf(v1);
    vT[((size_t)(h * 128 + 64 + lane)) * T_ + t] = f2bf(v2);
  }
}

// scores: per head [1024 x 1024 x 128]. grid (16, 16, 8), 2048 blocks (r9 verbatim)
__global__ __launch_bounds__(512) void k_scores(const u16* q, const u16* kb, u16* S) {
  __shared__ __align__(16) u16 A0[128 * LDP], B0[64 * LDP], A1[128 * LDP], B1[64 * LDP];
  int h = blockIdx.x, sn = blockIdx.y, qm = blockIdx.z;
  const u16* Aq = q + h * 128;
  const u16* Bk = kb + (size_t)(h >> 2) * T_ * HD_;
  f32x4 acc[2][2]; ZERO_ACC4(acc);
  auto la = [&](AU4& r, int kt) {
    r.v = *(const uint4*)(Aq + (size_t)(qm * 128 + (threadIdx.x >> 2)) * (NH_ * HD_) + kt * 32 + (threadIdx.x & 3) * 8);
  };
  auto lb = [&](BU2& r, int kt) {
    r.v = *(const uint2*)(Bk + (size_t)(sn * 64 + (threadIdx.x >> 3)) * HD_ + kt * 32 + (threadIdx.x & 7) * 4);
  };
  pipe2<HD_ / 32, AU4, BU2>(la, lb, A0, B0, A1, B1, acc);
  const float scale = 0.08838834764831845f;
#pragma unroll
  for (int m = 0; m < 2; ++m)
#pragma unroll
    for (int n = 0; n < 2; ++n) {
      f32x4 a = acc[m][n];
#pragma unroll
      for (int r = 0; r < 4; ++r)
        S[((size_t)h * T_ + qm * 128 + EPI_ROW(m, r)) * T_ + sn * 64 + EPI_COL(n)] =
            f2bf(a[r] * scale);
    }
}

__global__ __launch_bounds__(256) void k_softmax(u16* S) {
  __shared__ float lds[4];
  int t = blockIdx.x, h = blockIdx.y, tid = threadIdx.x;
  u16* rowp = S + ((size_t)h * T_ + t) * T_;
  float x[4];
#pragma unroll
  for (int i = 0; i < 4; ++i) x[i] = bf2f(rowp[tid + 256 * i]);
  float m = fmaxf(fmaxf(x[0], x[1]), fmaxf(x[2], x[3]));
  m = blk_max(m, lds);
  float s = 0.f;
#pragma unroll
  for (int i = 0; i < 4; ++i) { x[i] = __expf(x[i] - m); s += x[i]; }
  s = blk_sum(s, lds);
  float inv = 1.f / s;
#pragma unroll
  for (int i = 0; i < 4; ++i) rowp[tid + 256 * i] = f2bf(x[i] * inv);
}

// pv: per head [1024 x 128 x 1024]. grid (16, 8, 2), 256 blocks (r9 verbatim)
__global__ __launch_bounds__(512) void k_pv(const u16* P, const u16* vT, u16* ctx) {
  __shared__ __align__(16) u16 A0[128 * LDP], B0[64 * LDP], A1[128 * LDP], B1[64 * LDP];
  int h = blockIdx.x, qm = blockIdx.y, nb = blockIdx.z;
  const u16* Ap = P + (size_t)h * T_ * T_;
  const u16* Bv = vT + (size_t)(h >> 2) * HD_ * T_ + (size_t)nb * 64 * T_;
  f32x4 acc[2][2]; ZERO_ACC4(acc);
  auto la = [&](AU4& r, int kt) {
    r.v = *(const uint4*)(Ap + (size_t)(qm * 128 + (threadIdx.x >> 2)) * T_ + kt * 32 + (threadIdx.x & 3) * 8);
  };
  auto lb = [&](BU2& r, int kt) {
    r.v = *(const uint2*)(Bv + (size_t)(threadIdx.x >> 3) * T_ + kt * 32 + (threadIdx.x & 7) * 4);
  };
  pipe2<T_ / 32, AU4, BU2>(la, lb, A0, B0, A1, B1, acc);
#pragma unroll
  for (int m = 0; m < 2; ++m)
#pragma unroll
    for (int n = 0; n < 2; ++n) {
      f32x4 a = acc[m][n];
#pragma unroll
      for (int r = 0; r < 4; ++r)
        ctx[(size_t)(qm * 128 + EPI_ROW(m, r)) * (NH_ * HD_) + h * 128 + nb * 64 + EPI_COL(n)] =
            f2bf(a[r]);
    }
}

// wo: [1024 x 2048 x 2048], BN=32. grid (64, 8) = 512 blocks
__global__ __launch_bounds__(512) void k_wo(const u16* ctx, const float* wo,
                                            const float* hs, float* resid) {
  __shared__ __align__(16) u16 A0[128 * LDP], B0[32 * LDP], A1[128 * LDP], B1[32 * LDP];
  int bn = blockIdx.x, bm = blockIdx.y;
  f32x4 acc[2]; ZERO_ACC2(acc);
  auto la = [&](AU4& r, int kt) {
    r.v = *(const uint4*)(ctx + (size_t)(bm * 128 + (threadIdx.x >> 2)) * H_ + kt * 32 + (threadIdx.x & 3) * 8);
  };
  auto lb = [&](F2& r, int kt) {
    int n = threadIdx.x & 31, kh = (threadIdx.x >> 5) * 2;
    const float* src = wo + (size_t)(kt * 32 + kh) * H_ + bn * 32 + n;
    r.v[0] = src[0]; r.v[1] = src[H_];
  };
  pipeW<H_ / 32>(la, lb, A0, B0, A1, B1, acc);
#pragma unroll
  for (int n = 0; n < 2; ++n) {
    f32x4 a = acc[n];
#pragma unroll
    for (int r = 0; r < 4; ++r) {
      size_t idx = (size_t)(bm * 128 + EPIW_ROW(r)) * H_ + bn * 32 + EPIW_COL(n);
      resid[idx] = a[r] + hs[idx];
    }
  }
}

__global__ __launch_bounds__(256) void k_router(const float* h2f, const float* wr_,
                                                int* topi, float* topw, int* cnt) {
  __shared__ float xs[H_];
  __shared__ float red[4][16];
  __shared__ float lg[16];
  int t = blockIdx.x, tid = threadIdx.x;
#pragma unroll
  for (int i = 0; i < 8; ++i) xs[tid + 256 * i] = h2f[(size_t)t * H_ + tid + 256 * i];
  __syncthreads();
  int e = tid & 15, p = tid >> 4;
  float s = 0.f;
  int b0 = p * 128;
  for (int i = 0; i < 128; ++i) s += xs[b0 + i] * wr_[(size_t)(b0 + i) * E_ + e];
  s += __shfl_down(s, 32);
  s += __shfl_down(s, 16);
  int lane = tid & 63, w = tid >> 6;
  if (lane < 16) red[w][lane] = s;
  __syncthreads();
  if (tid < 16) lg[tid] = red[0][tid] + red[1][tid] + red[2][tid] + red[3][tid];
  __syncthreads();
  if (tid == 0) {
    float l1 = -1e30f; int e1 = 0;
    for (int i = 0; i < E_; ++i) if (lg[i] > l1) { l1 = lg[i]; e1 = i; }
    float l2 = -1e30f; int e2 = 0;
    for (int i = 0; i < E_; ++i) if (i != e1 && lg[i] > l2) { l2 = lg[i]; e2 = i; }
    float d = __expf(l2 - l1);
    float w1 = 1.f / (1.f + d), w2 = d / (1.f + d);
    topi[2 * t] = e1; topi[2 * t + 1] = e2;
    topw[2 * t] = w1; topw[2 * t + 1] = w2;
    atomicAdd(&cnt[e1], 1);
    atomicAdd(&cnt[e2], 1);
  }
}

__global__ void k_scan(const int* cnt, int* basearr) {
  if (threadIdx.x == 0) {
    int b = 0;
    for (int e = 0; e < E_; ++e) { basearr[e] = b; b += cnt[e]; }
    basearr[E_] = b;
  }
}

__global__ __launch_bounds__(256) void k_assign(const int* topi, const float* topw,
                                                const int* basearr, int* posc,
                                                int* tok, float* wslot) {
  int t = blockIdx.x * 256 + threadIdx.x;
  if (t < T_) {
#pragma unroll
    for (int j = 0; j < 2; ++j) {
      int e = topi[2 * t + j];
      int p = atomicAdd(&posc[e], 1);
      int s = basearr[e] + p;
      tok[s] = t;
      wslot[s] = topw[2 * t + j];
    }
  }
}

// gateup: 128 tokens x 16 out cols (32 LDS cols = [g:0..15 | u:16..31] of the SAME
// out cols). acc[0]=gate, acc[1]=up in the SAME lane. grid (16, 48, 8), ~768 active.
__global__ __launch_bounds__(512) void k_gateup(const u16* h2b,
                                                const float* wg, const float* wu,
                                                const int* cnt, const int* basearr, const int* tok,
                                                u16* act) {
  __shared__ __align__(16) u16 A0[128 * LDP], B0[32 * LDP], A1[128 * LDP], B1[32 * LDP];
  __shared__ int gat_s[128];
  int e = blockIdx.x;
  int c = cnt[e];
  int mt = blockIdx.z;
  if (mt * 128 >= c) return;
  int basee = basearr[e];
  int gmax = c - mt * 128;
  int n0 = blockIdx.y * 16;
  int tid = threadIdx.x;
  if (tid < 128) {
    int r = mt * 128 + tid;
    gat_s[tid] = (r < c) ? tok[basee + r] : tok[basee];
  }
  __syncthreads();
  const float* Bg = wg + (size_t)e * H_ * I_;
  const float* Bu = wu + (size_t)e * H_ * I_;
  f32x4 acc[2]; ZERO_ACC2(acc);
  auto la = [&](AU4& r, int kt) {
    r.v = *(const uint4*)(h2b + (size_t)gat_s[threadIdx.x >> 2] * H_ + kt * 32 + (threadIdx.x & 3) * 8);
  };
  auto lb = [&](F2& r, int kt) {
    int n = threadIdx.x & 31, kh = (threadIdx.x >> 5) * 2;
    const float* base = (n >= 16) ? Bu : Bg;
    int col = n0 + (n & 15);
    const float* src = base + (size_t)(kt * 32 + kh) * I_ + col;
    r.v[0] = src[0]; r.v[1] = src[I_];
  };
  pipeW<H_ / 32>(la, lb, A0, B0, A1, B1, acc);
  int slot0 = basee + mt * 128;
  int col = n0 + ((threadIdx.x & 63) & 15);
#pragma unroll
  for (int r = 0; r < 4; ++r) {
    int row = EPIW_ROW(r);
    if (row >= gmax) continue;
    float g = acc[0][r], u = acc[1][r];
    float sg = g / (1.f + __expf(-g));
    act[(size_t)(slot0 + row) * I_ + col] = f2bf(sg * u);
  }
}

// down: [slots x 2048 x 768], BN=32. grid (64, 16, 8), ~1024 active
__global__ __launch_bounds__(512) void k_down(const u16* act, const float* wd,
                                              const int* cnt, const int* basearr,
                                              const int* tok, const float* wslot,
                                              float* moe) {
  __shared__ __align__(16) u16 A0[128 * LDP], B0[32 * LDP], A1[128 * LDP], B1[32 * LDP];
  int e = blockIdx.y;
  int c = cnt[e];
  int mt = blockIdx.z;
  if (mt * 128 >= c) return;
  int basee = basearr[e];
  int gmax = c - mt * 128;
  int slot0 = basee + mt * 128;
  int n0 = blockIdx.x * 32;
  const u16* Ap = act + (size_t)slot0 * I_;
  const float* Bp = wd + (size_t)e * I_ * H_;
  f32x4 acc[2]; ZERO_ACC2(acc);
  auto la = [&](AU4& r, int kt) {
    r.v = *(const uint4*)(Ap + (size_t)(threadIdx.x >> 2) * I_ + kt * 32 + (threadIdx.x & 3) * 8);
  };
  auto lb = [&](F2& r, int kt) {
    int n = threadIdx.x & 31, kh = (threadIdx.x >> 5) * 2;
    const float* src = Bp + (size_t)(kt * 32 + kh) * H_ + n0 + n;
    r.v[0] = src[0]; r.v[1] = src[H_];
  };
  pipeW<I_ / 32>(la, lb, A0, B0, A1, B1, acc);
#pragma unroll
  for (int n = 0; n < 2; ++n) {
    f32x4 a = acc[n];
#pragma unroll
    for (int r = 0; r < 4; ++r) {
      int row = EPIW_ROW(r);
      if (row >= gmax) continue;
      int col = EPIW_COL(n);
      int slot = slot0 + row;
      float wgt = wslot[slot];
      int tk = tok[slot];
      atomicAdd(&moe[(size_t)tk * H_ + n0 + col], a[r] * wgt);
    }
  }
}

extern "C" void kernel_launch(void* const* d_in, const int* in_sizes, int n_in,
                              void* d_out, int out_size, void* d_ws, size_t ws_size,
                              hipStream_t stream) {
  const float* hs    = (const float*)d_in[0];
  const int*   pos   = (const int*)d_in[1];
  const float* wn1   = (const float*)d_in[2];
  const float* wn2   = (const float*)d_in[3];
  const float* wqkv  = (const float*)d_in[4];
  const float* wqn   = (const float*)d_in[5];
  const float* wkn   = (const float*)d_in[6];
  const float* wo    = (const float*)d_in[7];
  const float* wrt   = (const float*)d_in[8];
  const float* wg    = (const float*)d_in[9];
  const float* wu    = (const float*)d_in[10];
  const float* wd    = (const float*)d_in[11];
  float* out = (float*)d_out;
  float* moe_out = out;                       // T*H fp32
  float* resid   = out + (size_t)T_ * H_;     // T*H fp32

  char* ws = (char*)d_ws;
  size_t off = 0;
  auto alloc = [&](size_t bytes) { size_t r = off; off = (off + bytes + 255) & ~(size_t)255; return r; };
  u16*   h1   = (u16*)  (ws + alloc((size_t)T_ * H_ * 2));
  float* qkv  = (float*)(ws + alloc((size_t)T_ * QKVN * 4));
  u16*   q    = (u16*)  (ws + alloc((size_t)T_ * NH_ * HD_ * 2));
  u16*   kb   = (u16*)  (ws + alloc((size_t)NKV_ * T_ * HD_ * 2));
  u16*   vT   = (u16*)  (ws + alloc((size_t)NKV_ * HD_ * T_ * 2));
  u16*   S    = (u16*)  (ws + alloc((size_t)NH_ * T_ * T_ * 2));
  u16*   ctx  = (u16*)  (ws + alloc((size_t)T_ * NH_ * HD_ * 2));
  float* h2f  = (float*)(ws + alloc((size_t)T_ * H_ * 4));
  u16*   h2b  = (u16*)  (ws + alloc((size_t)T_ * H_ * 2));
  u16*   act  = (u16*)  (ws + alloc((size_t)(2 * T_ + 256) * I_ * 2));
  int*   topi = (int*)  (ws + alloc((size_t)T_ * 2 * 4));
  float* topw = (float*)(ws + alloc((size_t)T_ * 2 * 4));
  int*   cnt  = (int*)  (ws + alloc(32 * 4));
  int*   posc = cnt + 16;
  int*   base = (int*)  (ws + alloc(32 * 4));
  int*   tok  = (int*)  (ws + alloc((size_t)(2 * T_ + 128) * 4));
  float* wsl  = (float*)(ws + alloc((size_t)(2 * T_ + 128) * 4));
  (void)ws_size; (void)in_sizes; (void)n_in; (void)out_size;

  hipMemsetAsync(moe_out, 0, (size_t)T_ * H_ * 4, stream);
  hipMemsetAsync(cnt, 0, 32 * 4, stream);

  k_rms1<<<T_, 256, 0, stream>>>(hs, wn1, h1);
  k_qkv<<<dim3(QKVN / 32, T_ / 128), 512, 0, stream>>>(h1, wqkv, qkv);
  k_qkrope<<<T_, 256, 0, stream>>>(qkv, pos, wqn, wkn, q, kb, vT);
  k_scores<<<dim3(NH_, T_ / 64, T_ / 128), 512, 0, stream>>>(q, kb, S);
  k_softmax<<<dim3(T_, NH_), 256, 0, stream>>>(S);
  k_pv<<<dim3(NH_, T_ / 128, HD_ / 64), 512, 0, stream>>>(S, vT, ctx);
  k_wo<<<dim3(H_ / 32, T_ / 128), 512, 0, stream>>>(ctx, wo, hs, resid);
  k_rms2<<<T_, 256, 0, stream>>>(resid, wn2, h2f, h2b);
  k_router<<<T_, 256, 0, stream>>>(h2f, wrt, topi, topw, cnt);
  k_scan<<<1, 64, 0, stream>>>(cnt, base);
  k_assign<<<4, 256, 0, stream>>>(topi, topw, base, posc, tok, wsl);
  k_gateup<<<dim3(E_, I_ / 16, T_ / 128), 512, 0, stream>>>(h2b, wg, wu, cnt, base, tok, act);
  k_down<<<dim3(H_ / 32, E_, T_ / 128), 512, 0, stream>>>(act, wd, cnt, base, tok, wsl, moe_out);
}

// Round 13
// 340.520 us; speedup vs baseline: 1.1785x; 1.1785x over previous
//
#include <hip/hip_runtime.h>

#define T_    1024
#define H_    2048
#define NH_   16
#define NKV_  4
#define HD_   128
#define E_    16
#define I_    768
#define QKVN  3072

typedef __attribute__((ext_vector_type(8))) short  short8;
typedef __attribute__((ext_vector_type(4))) float  f32x4;
typedef unsigned short u16;

#define LDP 40   // padded LDS K-stride (bf16): 80B rows, 2-way banks at worst (free)

__device__ inline u16 f2bf(float f) {
  unsigned u = __builtin_bit_cast(unsigned, f);
  return (u16)((u + 0x7fffu + ((u >> 16) & 1u)) >> 16);
}
__device__ inline float bf2f(u16 h) {
  unsigned u = ((unsigned)h) << 16;
  return __builtin_bit_cast(float, u);
}

// GEMM barrier WITHOUT the __syncthreads vmcnt(0) drain: drain only LDS writes
// (lgkmcnt), then raw s_barrier. Prefetched global loads stay IN FLIGHT across
// the barrier; the compiler emits counted vmcnt(N) at the wrS that consumes them.
// (r12 lesson: __syncthreads -> s_waitcnt vmcnt(0) before s_barrier -> every
// K-step paid ~2x full HBM latency; occupancy couldn't mask it.)
__device__ inline void gemm_bar() {
  asm volatile("s_waitcnt lgkmcnt(0)" ::: "memory");
  __builtin_amdgcn_s_barrier();
}

__device__ inline float blk_sum(float v, float* lds) {
#pragma unroll
  for (int o = 32; o; o >>= 1) v += __shfl_down(v, o);
  int w = threadIdx.x >> 6;
  __syncthreads();
  if ((threadIdx.x & 63) == 0) lds[w] = v;
  __syncthreads();
  float s = lds[0];
  int nw = blockDim.x >> 6;
  for (int i = 1; i < nw; ++i) s += lds[i];
  return s;
}
__device__ inline float blk_max(float v, float* lds) {
#pragma unroll
  for (int o = 32; o; o >>= 1) v = fmaxf(v, __shfl_down(v, o));
  int w = threadIdx.x >> 6;
  __syncthreads();
  if ((threadIdx.x & 63) == 0) lds[w] = v;
  __syncthreads();
  float s = lds[0];
  int nw = blockDim.x >> 6;
  for (int i = 1; i < nw; ++i) s = fmaxf(s, lds[i]);
  return s;
}

// -------- GEMM template: 512 threads, 8 waves (4M x 2N), tile 128 x 64 x 32 --------
// Wave tile 32x32: acc[2][2] of 16x16x32 frags. Tiny per-thread prefetch slots
// (A: 1 uint4, B: 4 floats) -> proven no-spill regime (r9: VGPR 36, WRITE ~3MB).

struct AU4 { uint4 v; };       // A bf16: 128 rows x 32 k; row=tid>>2, kg=(tid&3)*8
struct BU2 { uint2 v; };       // B bf16: 64 rows x 32 k; row=tid>>3, kg=(tid&7)*4
struct F4  { float v[4]; };    // B fp32: 64 cols x 32 k; n=tid&63, kh=(tid>>6)*4

__device__ inline void wrS(u16* lds, const AU4& r) {
  *(uint4*)(lds + (threadIdx.x >> 2) * LDP + (threadIdx.x & 3) * 8) = r.v;
}
__device__ inline void wrS(u16* lds, const BU2& r) {
  *(uint2*)(lds + (threadIdx.x >> 3) * LDP + (threadIdx.x & 7) * 4) = r.v;
}
__device__ inline void wrS(u16* lds, const F4& r) {
  int n = threadIdx.x & 63, kh = (threadIdx.x >> 6) * 4;
  uint2 w;
  w.x = (unsigned)f2bf(r.v[0]) | ((unsigned)f2bf(r.v[1]) << 16);
  w.y = (unsigned)f2bf(r.v[2]) | ((unsigned)f2bf(r.v[3]) << 16);
  *(uint2*)(lds + n * LDP + kh) = w;
}

__device__ inline void mma2(const u16* As, const u16* Bs, f32x4 acc[2][2]) {
  const int lane = threadIdx.x & 63, wv = threadIdx.x >> 6;
  const int wr = wv >> 1, wc = wv & 1;
  const int kk = (lane >> 4) * 8, rr = lane & 15;
  short8 aF[2], bF[2];
#pragma unroll
  for (int m = 0; m < 2; ++m)
    aF[m] = *(const short8*)(As + (wr * 32 + m * 16 + rr) * LDP + kk);
#pragma unroll
  for (int n = 0; n < 2; ++n)
    bF[n] = *(const short8*)(Bs + (wc * 32 + n * 16 + rr) * LDP + kk);
#pragma unroll
  for (int m = 0; m < 2; ++m)
#pragma unroll
    for (int n = 0; n < 2; ++n)
      acc[m][n] = __builtin_amdgcn_mfma_f32_16x16x32_bf16(aF[m], bF[n], acc[m][n], 0, 0, 0);
}

#define ZERO_ACC(acc) do { \
  _Pragma("unroll") for (int m_ = 0; m_ < 2; ++m_) \
  _Pragma("unroll") for (int n_ = 0; n_ < 2; ++n_) acc[m_][n_] = (f32x4){0.f,0.f,0.f,0.f}; \
} while (0)

#define EPI_ROW(m, r)  (((threadIdx.x >> 6) >> 1) * 32 + (m)*16 + (((threadIdx.x&63) >> 4) * 4) + (r))
#define EPI_COL(n)     ((((threadIdx.x >> 6) & 1) * 32) + (n)*16 + ((threadIdx.x&63) & 15))

// Double-buffered LDS + 2-deep register prefetch (r8/r9-proven rotation), with
// counted-vmcnt barriers (gemm_bar). NT even >= 2.
// Invariant at loop head kt: LDS A0=tile kt, a1=kt+1, a0=kt+2.
template<int NT, class AT, class BT, class LA, class LB>
__device__ inline void pipe2(LA la, LB lb, u16* A0, u16* B0, u16* A1, u16* B1,
                             f32x4 acc[2][2]) {
  AT a0, a1; BT b0, b1;
  la(a0, 0); lb(b0, 0);
  la(a1, 1); lb(b1, 1);
  wrS(A0, a0); wrS(B0, b0);
  if (NT > 2) { la(a0, 2); lb(b0, 2); }
#pragma unroll 1
  for (int kt = 0; kt < NT; kt += 2) {
    gemm_bar();
    wrS(A1, a1); wrS(B1, b1);                       // tile kt+1
    if (kt + 3 < NT) { la(a1, kt + 3); lb(b1, kt + 3); }
    mma2(A0, B0, acc);                              // tile kt
    gemm_bar();
    if (kt + 2 < NT) { wrS(A0, a0); wrS(B0, b0); }  // tile kt+2
    if (kt + 4 < NT) { la(a0, kt + 4); lb(b0, kt + 4); }
    mma2(A1, B1, acc);                              // tile kt+1
  }
}

// ---------------- kernels ----------------

__global__ __launch_bounds__(256) void k_rms1(const float* x, const float* w, u16* out) {
  __shared__ float lds[4];
  int t = blockIdx.x, tid = threadIdx.x;
  float v[8]; float ss = 0.f;
#pragma unroll
  for (int i = 0; i < 8; ++i) { v[i] = x[(size_t)t * H_ + tid + 256 * i]; ss += v[i] * v[i]; }
  ss = blk_sum(ss, lds);
  float inv = rsqrtf(ss * (1.f / H_) + 1e-6f);
#pragma unroll
  for (int i = 0; i < 8; ++i)
    out[(size_t)t * H_ + tid + 256 * i] = f2bf(v[i] * inv * w[tid + 256 * i]);
}

__global__ __launch_bounds__(256) void k_rms2(const float* x, const float* w,
                                              float* outf, u16* outb) {
  __shared__ float lds[4];
  int t = blockIdx.x, tid = threadIdx.x;
  float v[8]; float ss = 0.f;
#pragma unroll
  for (int i = 0; i < 8; ++i) { v[i] = x[(size_t)t * H_ + tid + 256 * i]; ss += v[i] * v[i]; }
  ss = blk_sum(ss, lds);
  float inv = rsqrtf(ss * (1.f / H_) + 1e-6f);
#pragma unroll
  for (int i = 0; i < 8; ++i) {
    float r = v[i] * inv * w[tid + 256 * i];
    outf[(size_t)t * H_ + tid + 256 * i] = r;
    outb[(size_t)t * H_ + tid + 256 * i] = f2bf(r);
  }
}

// qkv: [1024 x 3072 x 2048]. grid (48, 8), 384 blocks
__global__ __launch_bounds__(512) void k_qkv(const u16* h1, const float* wqkv, float* qkv) {
  __shared__ __align__(16) u16 A0[128 * LDP], B0[64 * LDP], A1[128 * LDP], B1[64 * LDP];
  int bn = blockIdx.x, bm = blockIdx.y;
  f32x4 acc[2][2]; ZERO_ACC(acc);
  auto la = [&](AU4& r, int kt) {
    r.v = *(const uint4*)(h1 + (size_t)(bm * 128 + (threadIdx.x >> 2)) * H_ + kt * 32 + (threadIdx.x & 3) * 8);
  };
  auto lb = [&](F4& r, int kt) {
    int n = threadIdx.x & 63, kh = (threadIdx.x >> 6) * 4;
    const float* src = wqkv + (size_t)(kt * 32 + kh) * QKVN + bn * 64 + n;
#pragma unroll
    for (int j = 0; j < 4; ++j) r.v[j] = src[(size_t)j * QKVN];
  };
  pipe2<H_ / 32, AU4, F4>(la, lb, A0, B0, A1, B1, acc);
#pragma unroll
  for (int m = 0; m < 2; ++m)
#pragma unroll
    for (int n = 0; n < 2; ++n) {
      f32x4 a = acc[m][n];
#pragma unroll
      for (int r = 0; r < 4; ++r)
        qkv[(size_t)(bm * 128 + EPI_ROW(m, r)) * QKVN + bn * 64 + EPI_COL(n)] = a[r];
    }
}

__global__ __launch_bounds__(256) void k_qkrope(const float* qkv, const int* pos,
                                                const float* wq, const float* wk,
                                                u16* q, u16* kk, u16* vT) {
  __shared__ float cs[64], sn[64];
  int t = blockIdx.x, tid = threadIdx.x, lane = tid & 63, w = tid >> 6;
  if (tid < 64) {
    float fr = expf(-((float)tid / 64.f) * 9.210340371976184f);
    float ang = (float)pos[t] * fr;
    float s_, c_; sincosf(ang, &s_, &c_);
    cs[tid] = c_; sn[tid] = s_;
  }
  __syncthreads();
  const float* row = qkv + (size_t)t * QKVN;
  for (int h = w; h < NH_; h += 4) {
    float x1 = row[h * 128 + lane], x2 = row[h * 128 + 64 + lane];
    float ss = x1 * x1 + x2 * x2;
#pragma unroll
    for (int o = 32; o; o >>= 1) ss += __shfl_down(ss, o);
    ss = __shfl(ss, 0);
    float inv = rsqrtf(ss * (1.f / HD_) + 1e-6f);
    float n1 = x1 * inv * wq[lane], n2 = x2 * inv * wq[64 + lane];
    float o1 = n1 * cs[lane] - n2 * sn[lane];
    float o2 = n2 * cs[lane] + n1 * sn[lane];
    q[(size_t)t * (NH_ * HD_) + h * 128 + lane] = f2bf(o1);
    q[(size_t)t * (NH_ * HD_) + h * 128 + 64 + lane] = f2bf(o2);
  }
  if (w < NKV_) {
    int h = w;
    float x1 = row[2048 + h * 128 + lane], x2 = row[2048 + h * 128 + 64 + lane];
    float ss = x1 * x1 + x2 * x2;
#pragma unroll
    for (int o = 32; o; o >>= 1) ss += __shfl_down(ss, o);
    ss = __shfl(ss, 0);
    float inv = rsqrtf(ss * (1.f / HD_) + 1e-6f);
    float n1 = x1 * inv * wk[lane], n2 = x2 * inv * wk[64 + lane];
    float o1 = n1 * cs[lane] - n2 * sn[lane];
    float o2 = n2 * cs[lane] + n1 * sn[lane];
    kk[((size_t)h * T_ + t) * HD_ + lane] = f2bf(o1);
    kk[((size_t)h * T_ + t) * HD_ + 64 + lane] = f2bf(o2);
    float v1 = row[2560 + h * 128 + lane], v2 = row[2560 + h * 128 + 64 + lane];
    vT[((size_t)(h * 128 + lane)) * T_ + t] = f2bf(v1);
    vT[((size_t)(h * 128 + 64 + lane)) * T_ + t] = f2bf(v2);
  }
}

// scores: per head [1024 x 1024 x 128]. grid (16, 16, 8), 2048 blocks
__global__ __launch_bounds__(512) void k_scores(const u16* q, const u16* kb, u16* S) {
  __shared__ __align__(16) u16 A0[128 * LDP], B0[64 * LDP], A1[128 * LDP], B1[64 * LDP];
  int h = blockIdx.x, sn = blockIdx.y, qm = blockIdx.z;
  const u16* Aq = q + h * 128;
  const u16* Bk = kb + (size_t)(h >> 2) * T_ * HD_;
  f32x4 acc[2][2]; ZERO_ACC(acc);
  auto la = [&](AU4& r, int kt) {
    r.v = *(const uint4*)(Aq + (size_t)(qm * 128 + (threadIdx.x >> 2)) * (NH_ * HD_) + kt * 32 + (threadIdx.x & 3) * 8);
  };
  auto lb = [&](BU2& r, int kt) {
    r.v = *(const uint2*)(Bk + (size_t)(sn * 64 + (threadIdx.x >> 3)) * HD_ + kt * 32 + (threadIdx.x & 7) * 4);
  };
  pipe2<HD_ / 32, AU4, BU2>(la, lb, A0, B0, A1, B1, acc);
  const float scale = 0.08838834764831845f;
#pragma unroll
  for (int m = 0; m < 2; ++m)
#pragma unroll
    for (int n = 0; n < 2; ++n) {
      f32x4 a = acc[m][n];
#pragma unroll
      for (int r = 0; r < 4; ++r)
        S[((size_t)h * T_ + qm * 128 + EPI_ROW(m, r)) * T_ + sn * 64 + EPI_COL(n)] =
            f2bf(a[r] * scale);
    }
}

__global__ __launch_bounds__(256) void k_softmax(u16* S) {
  __shared__ float lds[4];
  int t = blockIdx.x, h = blockIdx.y, tid = threadIdx.x;
  u16* rowp = S + ((size_t)h * T_ + t) * T_;
  float x[4];
#pragma unroll
  for (int i = 0; i < 4; ++i) x[i] = bf2f(rowp[tid + 256 * i]);
  float m = fmaxf(fmaxf(x[0], x[1]), fmaxf(x[2], x[3]));
  m = blk_max(m, lds);
  float s = 0.f;
#pragma unroll
  for (int i = 0; i < 4; ++i) { x[i] = __expf(x[i] - m); s += x[i]; }
  s = blk_sum(s, lds);
  float inv = 1.f / s;
#pragma unroll
  for (int i = 0; i < 4; ++i) rowp[tid + 256 * i] = f2bf(x[i] * inv);
}

// pv: per head [1024 x 128 x 1024]. grid (16, 8, 2), 256 blocks
__global__ __launch_bounds__(512) void k_pv(const u16* P, const u16* vT, u16* ctx) {
  __shared__ __align__(16) u16 A0[128 * LDP], B0[64 * LDP], A1[128 * LDP], B1[64 * LDP];
  int h = blockIdx.x, qm = blockIdx.y, nb = blockIdx.z;
  const u16* Ap = P + (size_t)h * T_ * T_;
  const u16* Bv = vT + (size_t)(h >> 2) * HD_ * T_ + (size_t)nb * 64 * T_;
  f32x4 acc[2][2]; ZERO_ACC(acc);
  auto la = [&](AU4& r, int kt) {
    r.v = *(const uint4*)(Ap + (size_t)(qm * 128 + (threadIdx.x >> 2)) * T_ + kt * 32 + (threadIdx.x & 3) * 8);
  };
  auto lb = [&](BU2& r, int kt) {
    r.v = *(const uint2*)(Bv + (size_t)(threadIdx.x >> 3) * T_ + kt * 32 + (threadIdx.x & 7) * 4);
  };
  pipe2<T_ / 32, AU4, BU2>(la, lb, A0, B0, A1, B1, acc);
#pragma unroll
  for (int m = 0; m < 2; ++m)
#pragma unroll
    for (int n = 0; n < 2; ++n) {
      f32x4 a = acc[m][n];
#pragma unroll
      for (int r = 0; r < 4; ++r)
        ctx[(size_t)(qm * 128 + EPI_ROW(m, r)) * (NH_ * HD_) + h * 128 + nb * 64 + EPI_COL(n)] =
            f2bf(a[r]);
    }
}

// wo: [1024 x 2048 x 2048]. grid (32, 8), 256 blocks
__global__ __launch_bounds__(512) void k_wo(const u16* ctx, const float* wo,
                                            const float* hs, float* resid) {
  __shared__ __align__(16) u16 A0[128 * LDP], B0[64 * LDP], A1[128 * LDP], B1[64 * LDP];
  int bn = blockIdx.x, bm = blockIdx.y;
  f32x4 acc[2][2]; ZERO_ACC(acc);
  auto la = [&](AU4& r, int kt) {
    r.v = *(const uint4*)(ctx + (size_t)(bm * 128 + (threadIdx.x >> 2)) * H_ + kt * 32 + (threadIdx.x & 3) * 8);
  };
  auto lb = [&](F4& r, int kt) {
    int n = threadIdx.x & 63, kh = (threadIdx.x >> 6) * 4;
    const float* src = wo + (size_t)(kt * 32 + kh) * H_ + bn * 64 + n;
#pragma unroll
    for (int j = 0; j < 4; ++j) r.v[j] = src[(size_t)j * H_];
  };
  pipe2<H_ / 32, AU4, F4>(la, lb, A0, B0, A1, B1, acc);
#pragma unroll
  for (int m = 0; m < 2; ++m)
#pragma unroll
    for (int n = 0; n < 2; ++n) {
      f32x4 a = acc[m][n];
#pragma unroll
      for (int r = 0; r < 4; ++r) {
        size_t idx = (size_t)(bm * 128 + EPI_ROW(m, r)) * H_ + bn * 64 + EPI_COL(n);
        resid[idx] = a[r] + hs[idx];
      }
    }
}

__global__ __launch_bounds__(256) void k_router(const float* h2f, const float* wr_,
                                                int* topi, float* topw, int* cnt) {
  __shared__ float xs[H_];
  __shared__ float red[4][16];
  __shared__ float lg[16];
  int t = blockIdx.x, tid = threadIdx.x;
#pragma unroll
  for (int i = 0; i < 8; ++i) xs[tid + 256 * i] = h2f[(size_t)t * H_ + tid + 256 * i];
  __syncthreads();
  int e = tid & 15, p = tid >> 4;
  float s = 0.f;
  int b0 = p * 128;
  for (int i = 0; i < 128; ++i) s += xs[b0 + i] * wr_[(size_t)(b0 + i) * E_ + e];
  s += __shfl_down(s, 32);
  s += __shfl_down(s, 16);
  int lane = tid & 63, w = tid >> 6;
  if (lane < 16) red[w][lane] = s;
  __syncthreads();
  if (tid < 16) lg[tid] = red[0][tid] + red[1][tid] + red[2][tid] + red[3][tid];
  __syncthreads();
  if (tid == 0) {
    float l1 = -1e30f; int e1 = 0;
    for (int i = 0; i < E_; ++i) if (lg[i] > l1) { l1 = lg[i]; e1 = i; }
    float l2 = -1e30f; int e2 = 0;
    for (int i = 0; i < E_; ++i) if (i != e1 && lg[i] > l2) { l2 = lg[i]; e2 = i; }
    float d = __expf(l2 - l1);
    float w1 = 1.f / (1.f + d), w2 = d / (1.f + d);
    topi[2 * t] = e1; topi[2 * t + 1] = e2;
    topw[2 * t] = w1; topw[2 * t + 1] = w2;
    atomicAdd(&cnt[e1], 1);
    atomicAdd(&cnt[e2], 1);
  }
}

__global__ void k_scan(const int* cnt, int* basearr) {
  if (threadIdx.x == 0) {
    int b = 0;
    for (int e = 0; e < E_; ++e) { basearr[e] = b; b += cnt[e]; }
    basearr[E_] = b;
  }
}

__global__ __launch_bounds__(256) void k_assign(const int* topi, const float* topw,
                                                const int* basearr, int* posc,
                                                int* tok, float* wslot) {
  int t = blockIdx.x * 256 + threadIdx.x;
  if (t < T_) {
#pragma unroll
    for (int j = 0; j < 2; ++j) {
      int e = topi[2 * t + j];
      int p = atomicAdd(&posc[e], 1);
      int s = basearr[e] + p;
      tok[s] = t;
      wslot[s] = topw[2 * t + j];
    }
  }
}

// gateup: 128 tokens x 32 out cols per block (64 LDS cols interleave g|u at
// 16-col granularity). acc[m][0]=gate, acc[m][1]=up in the SAME lane.
// grid (16, 24, 8), ~384 active.
__global__ __launch_bounds__(512) void k_gateup(const u16* h2b,
                                                const float* wg, const float* wu,
                                                const int* cnt, const int* basearr, const int* tok,
                                                u16* act) {
  __shared__ __align__(16) u16 A0[128 * LDP], B0[64 * LDP], A1[128 * LDP], B1[64 * LDP];
  __shared__ int gat_s[128];
  int e = blockIdx.x;
  int c = cnt[e];
  int mt = blockIdx.z;
  if (mt * 128 >= c) return;
  int basee = basearr[e];
  int gmax = c - mt * 128;
  int n0 = blockIdx.y * 32;
  int tid = threadIdx.x;
  if (tid < 128) {
    int r = mt * 128 + tid;
    gat_s[tid] = (r < c) ? tok[basee + r] : tok[basee];
  }
  __syncthreads();
  const float* Bg = wg + (size_t)e * H_ * I_;
  const float* Bu = wu + (size_t)e * H_ * I_;
  f32x4 acc[2][2]; ZERO_ACC(acc);
  auto la = [&](AU4& r, int kt) {
    r.v = *(const uint4*)(h2b + (size_t)gat_s[threadIdx.x >> 2] * H_ + kt * 32 + (threadIdx.x & 3) * 8);
  };
  auto lb = [&](F4& r, int kt) {
    int cidx = threadIdx.x & 63, kh = (threadIdx.x >> 6) * 4;
    int fn = cidx >> 4;                       // 0..3
    const float* base = (fn & 1) ? Bu : Bg;
    int col = n0 + (fn >> 1) * 16 + (cidx & 15);
    const float* src = base + (size_t)(kt * 32 + kh) * I_ + col;
#pragma unroll
    for (int j = 0; j < 4; ++j) r.v[j] = src[(size_t)j * I_];
  };
  pipe2<H_ / 32, AU4, F4>(la, lb, A0, B0, A1, B1, acc);
  int slot0 = basee + mt * 128;
  int col = n0 + ((threadIdx.x >> 6) & 1) * 16 + ((threadIdx.x & 63) & 15);
#pragma unroll
  for (int m = 0; m < 2; ++m) {
#pragma unroll
    for (int r = 0; r < 4; ++r) {
      int row = EPI_ROW(m, r);
      if (row >= gmax) continue;
      float g = acc[m][0][r], u = acc[m][1][r];
      float sg = g / (1.f + __expf(-g));
      act[(size_t)(slot0 + row) * I_ + col] = f2bf(sg * u);
    }
  }
}

// down: [slots x 2048 x 768]. grid (32, 16, 8), ~512 active
__global__ __launch_bounds__(512) void k_down(const u16* act, const float* wd,
                                              const int* cnt, const int* basearr,
                                              const int* tok, const float* wslot,
                                              float* moe) {
  __shared__ __align__(16) u16 A0[128 * LDP], B0[64 * LDP], A1[128 * LDP], B1[64 * LDP];
  int e = blockIdx.y;
  int c = cnt[e];
  int mt = blockIdx.z;
  if (mt * 128 >= c) return;
  int basee = basearr[e];
  int gmax = c - mt * 128;
  int slot0 = basee + mt * 128;
  int n0 = blockIdx.x * 64;
  const u16* Ap = act + (size_t)slot0 * I_;
  const float* Bp = wd + (size_t)e * I_ * H_;
  f32x4 acc[2][2]; ZERO_ACC(acc);
  auto la = [&](AU4& r, int kt) {
    r.v = *(const uint4*)(Ap + (size_t)(threadIdx.x >> 2) * I_ + kt * 32 + (threadIdx.x & 3) * 8);
  };
  auto lb = [&](F4& r, int kt) {
    int n = threadIdx.x & 63, kh = (threadIdx.x >> 6) * 4;
    const float* src = Bp + (size_t)(kt * 32 + kh) * H_ + n0 + n;
#pragma unroll
    for (int j = 0; j < 4; ++j) r.v[j] = src[(size_t)j * H_];
  };
  pipe2<I_ / 32, AU4, F4>(la, lb, A0, B0, A1, B1, acc);
#pragma unroll
  for (int m = 0; m < 2; ++m)
#pragma unroll
    for (int n = 0; n < 2; ++n) {
      f32x4 a = acc[m][n];
#pragma unroll
      for (int r = 0; r < 4; ++r) {
        int row = EPI_ROW(m, r);
        if (row >= gmax) continue;
        int col = EPI_COL(n);
        int slot = slot0 + row;
        float wgt = wslot[slot];
        int tk = tok[slot];
        atomicAdd(&moe[(size_t)tk * H_ + n0 + col], a[r] * wgt);
      }
    }
}

extern "C" void kernel_launch(void* const* d_in, const int* in_sizes, int n_in,
                              void* d_out, int out_size, void* d_ws, size_t ws_size,
                              hipStream_t stream) {
  const float* hs    = (const float*)d_in[0];
  const int*   pos   = (const int*)d_in[1];
  const float* wn1   = (const float*)d_in[2];
  const float* wn2   = (const float*)d_in[3];
  const float* wqkv  = (const float*)d_in[4];
  const float* wqn   = (const float*)d_in[5];
  const float* wkn   = (const float*)d_in[6];
  const float* wo    = (const float*)d_in[7];
  const float* wrt   = (const float*)d_in[8];
  const float* wg    = (const float*)d_in[9];
  const float* wu    = (const float*)d_in[10];
  const float* wd    = (const float*)d_in[11];
  float* out = (float*)d_out;
  float* moe_out = out;                       // T*H fp32
  float* resid   = out + (size_t)T_ * H_;     // T*H fp32

  char* ws = (char*)d_ws;
  size_t off = 0;
  auto alloc = [&](size_t bytes) { size_t r = off; off = (off + bytes + 255) & ~(size_t)255; return r; };
  u16*   h1   = (u16*)  (ws + alloc((size_t)T_ * H_ * 2));
  float* qkv  = (float*)(ws + alloc((size_t)T_ * QKVN * 4));
  u16*   q    = (u16*)  (ws + alloc((size_t)T_ * NH_ * HD_ * 2));
  u16*   kb   = (u16*)  (ws + alloc((size_t)NKV_ * T_ * HD_ * 2));
  u16*   vT   = (u16*)  (ws + alloc((size_t)NKV_ * HD_ * T_ * 2));
  u16*   S    = (u16*)  (ws + alloc((size_t)NH_ * T_ * T_ * 2));
  u16*   ctx  = (u16*)  (ws + alloc((size_t)T_ * NH_ * HD_ * 2));
  float* h2f  = (float*)(ws + alloc((size_t)T_ * H_ * 4));
  u16*   h2b  = (u16*)  (ws + alloc((size_t)T_ * H_ * 2));
  u16*   act  = (u16*)  (ws + alloc((size_t)(2 * T_ + 256) * I_ * 2));
  int*   topi = (int*)  (ws + alloc((size_t)T_ * 2 * 4));
  float* topw = (float*)(ws + alloc((size_t)T_ * 2 * 4));
  int*   cnt  = (int*)  (ws + alloc(32 * 4));
  int*   posc = cnt + 16;
  int*   base = (int*)  (ws + alloc(32 * 4));
  int*   tok  = (int*)  (ws + alloc((size_t)(2 * T_ + 128) * 4));
  float* wsl  = (float*)(ws + alloc((size_t)(2 * T_ + 128) * 4));
  (void)ws_size; (void)in_sizes; (void)n_in; (void)out_size;

  hipMemsetAsync(moe_out, 0, (size_t)T_ * H_ * 4, stream);
  hipMemsetAsync(cnt, 0, 32 * 4, stream);

  k_rms1<<<T_, 256, 0, stream>>>(hs, wn1, h1);
  k_qkv<<<dim3(QKVN / 64, T_ / 128), 512, 0, stream>>>(h1, wqkv, qkv);
  k_qkrope<<<T_, 256, 0, stream>>>(qkv, pos, wqn, wkn, q, kb, vT);
  k_scores<<<dim3(NH_, T_ / 64, T_ / 128), 512, 0, stream>>>(q, kb, S);
  k_softmax<<<dim3(T_, NH_), 256, 0, stream>>>(S);
  k_pv<<<dim3(NH_, T_ / 128, HD_ / 64), 512, 0, stream>>>(S, vT, ctx);
  k_wo<<<dim3(H_ / 64, T_ / 128), 512, 0, stream>>>(ctx, wo, hs, resid);
  k_rms2<<<T_, 256, 0, stream>>>(resid, wn2, h2f, h2b);
  k_router<<<T_, 256, 0, stream>>>(h2f, wrt, topi, topw, cnt);
  k_scan<<<1, 64, 0, stream>>>(cnt, base);
  k_assign<<<4, 256, 0, stream>>>(topi, topw, base, posc, tok, wsl);
  k_gateup<<<dim3(E_, I_ / 32, T_ / 128), 512, 0, stream>>>(h2b, wg, wu, cnt, base, tok, act);
  k_down<<<dim3(H_ / 64, E_, T_ / 128), 512, 0, stream>>>(act, wd, cnt, base, tok, wsl, moe_out);
}